// Round 6
// baseline (2203.980 us; speedup 1.0000x reference)
//
#include <hip/hip_runtime.h>

#define HD 256
#define ID 32
#define OD 10
#define SEQ 512
#define NBG 16
#define FLAGS_OFF 589824            // after 576 KB packed weights
#define HX_OFF    622592            // after flags region
#define SMEM_BYTES (16384 + 65536)  // hbuf[2][16][256] + 8 waves x 8 LDS frags

typedef __attribute__((ext_vector_type(4))) float f32x4;
typedef __attribute__((ext_vector_type(8))) unsigned short u16x8;
typedef __attribute__((ext_vector_type(8))) __bf16 bf16x8;

static __device__ __forceinline__ unsigned short f2bf(float f) {
  unsigned u = __builtin_bit_cast(unsigned, f);
  u += 0x7fffu + ((u >> 16) & 1u);          // RNE
  return (unsigned short)(u >> 16);
}
static __device__ __forceinline__ float bf2f(unsigned short s) {
  unsigned u = ((unsigned)s) << 16;
  return __builtin_bit_cast(float, u);
}
static __device__ __forceinline__ f32x4 mfma16(u16x8 a, u16x8 b, f32x4 c) {
  return __builtin_amdgcn_mfma_f32_16x16x32_bf16(
      __builtin_bit_cast(bf16x8, a), __builtin_bit_cast(bf16x8, b), c, 0, 0, 0);
}
static __device__ __forceinline__ float fast_sigmoid(float x) {
  return 1.f / (1.f + __expf(-x));
}
static __device__ __forceinline__ float fast_tanh(float x) {
  return 1.f - 2.f / (__expf(2.f * x) + 1.f);
}

// ---------------------------------------------------------------------------
// Pack weights fragment-major (round-4 geometry, unchanged).
// hw = hf*8 + w (0..15), frag id f = hw*36 + g*9 + kt.
// lane l slot i -> W[k = 32kt + 8*(l>>4) + i][unit U = hw*16 + (l&15)] (gate g)
// ---------------------------------------------------------------------------
__global__ void pack_w(const float* __restrict__ Wgx, const float* __restrict__ Wgh,
                       const float* __restrict__ Wix, const float* __restrict__ Wih,
                       const float* __restrict__ Wfx, const float* __restrict__ Wfh,
                       const float* __restrict__ Wox, const float* __restrict__ Woh,
                       unsigned short* __restrict__ Wpk) {
  int p = blockIdx.x * blockDim.x + threadIdx.x;
  if (p >= 576 * 64) return;
  int f = p >> 6, l = p & 63;
  int hw = f / 36, r = f % 36;
  int g = r / 9, kt = r % 9;
  int U = hw * 16 + (l & 15);
  const float* Wx[4] = {Wgx, Wix, Wfx, Wox};
  const float* Wh[4] = {Wgh, Wih, Wfh, Woh};
  u16x8 v;
  #pragma unroll
  for (int i = 0; i < 8; ++i) {
    int k = kt * 32 + 8 * (l >> 4) + i;
    float val = (k < ID) ? Wx[g][k * HD + U] : Wh[g][(k - ID) * HD + U];
    v[i] = f2bf(val);
  }
  *(u16x8*)(Wpk + ((size_t)f << 9) + (l << 3)) = v;
}

template <int HF>
static __device__ __forceinline__ void mfma_own(
    const u16x8 (&wf)[4][7], const unsigned short* wlds_w, int l,
    const u16x8& ax, const u16x8 (&aown)[4], f32x4 (&acc)[4], bool full) {
  #pragma unroll
  for (int g = 0; g < 4; ++g) acc[g] = mfma16(ax, wf[g][0], acc[g]);
  if (!full) return;
  #pragma unroll
  for (int k2 = 0; k2 < 4; ++k2) {
    const int kt = 1 + 4 * HF + k2;
    #pragma unroll
    for (int g = 0; g < 4; ++g) {
      u16x8 bw;
      if (kt <= 6) bw = wf[g][kt];
      else bw = *(const u16x8*)(wlds_w + (g * 2 + (kt - 7)) * 512 + l * 8);
      acc[g] = mfma16(aown[k2], bw, acc[g]);
    }
  }
}
template <int HF>
static __device__ __forceinline__ void mfma_part(
    const u16x8 (&wf)[4][7], const unsigned short* wlds_w, int l,
    const u16x8 (&apart)[4], f32x4 (&acc)[4]) {
  #pragma unroll
  for (int k2 = 0; k2 < 4; ++k2) {
    const int kt = 1 + 4 * (1 - HF) + k2;
    #pragma unroll
    for (int g = 0; g < 4; ++g) {
      u16x8 bw;
      if (kt <= 6) bw = wf[g][kt];
      else bw = *(const u16x8*)(wlds_w + (g * 2 + (kt - 7)) * 512 + l * 8);
      acc[g] = mfma16(apart[k2], bw, acc[g]);
    }
  }
}

// ---------------------------------------------------------------------------
// 32 WGs = 16 batch-groups x 2 hidden-halves; 512 threads (8 waves).
// Weights resident (28 VGPR/AGPR + 8 LDS frags per wave).
// Exchange: plain 8B/thread publish + one release-flag; consumer polls
// relaxed, one acquire-fence, plain 16B loads straight into A-fragments.
// hx data layout: [parity][bgi][hf] 4KB = [16 rows][128 ushorts] row-major.
// ---------------------------------------------------------------------------
__global__ void __launch_bounds__(512, 2) lstm_rec(
    const float* __restrict__ x, const unsigned short* __restrict__ Wpk,
    const float* __restrict__ bgp, const float* __restrict__ bip,
    const float* __restrict__ bfp, const float* __restrict__ bop,
    const float* __restrict__ Wph, const float* __restrict__ bpp,
    unsigned int* __restrict__ flags, void* __restrict__ hx,
    float* __restrict__ out) {
  extern __shared__ __align__(16) char smem[];
  unsigned short* hbuf = (unsigned short*)smem;            // [2][16][256] bf16
  unsigned short* wlds = (unsigned short*)(smem + 16384);  // [8][8*512]

  const int tid = threadIdx.x;
  const int w = tid >> 6, l = tid & 63;
  const int l15 = l & 15, l4 = l >> 4;
  const int bgi = blockIdx.x & 15, hf = blockIdx.x >> 4;
  const int b0 = bgi * 16;
  char* hxc = (char*)hx;
  unsigned int* myflag = flags + (bgi * 2 + hf) * 32;      // 128B apart
  unsigned int* pflag  = flags + (bgi * 2 + (1 - hf)) * 32;

  const unsigned short* wbase =
      Wpk + (((size_t)(hf * 8 + w) * 36) << 9) + (l << 3);
  unsigned short* wlds_w = wlds + w * 4096;

  // stage kt7,8 frags to LDS
  #pragma unroll
  for (int g = 0; g < 4; ++g)
    #pragma unroll
    for (int d = 0; d < 2; ++d) {
      u16x8 v = *(const u16x8*)(wbase + ((size_t)(g * 9 + 7 + d) << 9));
      *(u16x8*)(wlds_w + (g * 2 + d) * 512 + l * 8) = v;
    }
  // resident frags kt 0..6 (VGPR+AGPR)
  u16x8 wf[4][7];
  #pragma unroll
  for (int g = 0; g < 4; ++g)
    #pragma unroll
    for (int kt = 0; kt < 7; ++kt)
      wf[g][kt] = *(const u16x8*)(wbase + ((size_t)(g * 9 + kt) << 9));

  float bias[4];
  {
    const float* bs[4] = {bgp, bip, bfp, bop};
    #pragma unroll
    for (int g = 0; g < 4; ++g) bias[g] = bs[g][hf * 128 + w * 16 + l15];
  }
  float cst[4] = {0.f, 0.f, 0.f, 0.f};

  const float* xrow = x + ((size_t)(b0 + l15) * SEQ) * ID + 8 * l4;
  float4 xv0 = *(const float4*)xrow;
  float4 xv1 = *(const float4*)(xrow + 4);

  // publish slot for this thread (pack readback): row ro, 4 units from u0
  const int ro = tid >> 5, u0 = (tid & 31) * 4;
  const int pgu = hf * 128 + u0;
  const int pofs = ro * 256 + ((((pgu >> 3) ^ ro) & 31) * 8) + (pgu & 7);

  __syncthreads();

  #pragma unroll 1
  for (int t = 0; t < SEQ; ++t) {
    u16x8 ax;
    ax[0] = f2bf(xv0.x); ax[1] = f2bf(xv0.y); ax[2] = f2bf(xv0.z); ax[3] = f2bf(xv0.w);
    ax[4] = f2bf(xv1.x); ax[5] = f2bf(xv1.y); ax[6] = f2bf(xv1.z); ax[7] = f2bf(xv1.w);
    {
      int tn = (t + 1 < SEQ) ? (t + 1) : t;
      xv0 = *(const float4*)(xrow + (size_t)tn * ID);
      xv1 = *(const float4*)(xrow + (size_t)tn * ID + 4);
    }

    const int pr = (t - 1) & 1;          // parity holding h_{t-1}
    u16x8 aown[4], apart[4];
    if (t > 0) {
      // wait for partner h_{t-1} (relaxed poll; single acquire fence)
      while (__hip_atomic_load(pflag, __ATOMIC_RELAXED,
                               __HIP_MEMORY_SCOPE_AGENT) < (unsigned)t) {}
      __builtin_amdgcn_fence(__ATOMIC_ACQUIRE, "agent");
      // partner half: plain 16B loads straight into A-fragments
      const unsigned short* pp = (const unsigned short*)
          (hxc + (size_t)((pr * NBG + bgi) * 2 + (1 - hf)) * 4096) + l15 * 128;
      #pragma unroll
      for (int k2 = 0; k2 < 4; ++k2)
        apart[k2] = *(const u16x8*)(pp + 32 * k2 + 8 * l4);
      // own half from swizzled LDS
      const unsigned short* hb = hbuf + pr * 4096 + l15 * 256;
      #pragma unroll
      for (int k2 = 0; k2 < 4; ++k2) {
        int c = 4 * (4 * hf + k2) + l4;
        aown[k2] = *(const u16x8*)(hb + ((c ^ l15) & 31) * 8);
      }
    }

    f32x4 acc[4];
    #pragma unroll
    for (int g = 0; g < 4; ++g)
      acc[g] = f32x4{bias[g], bias[g], bias[g], bias[g]};
    if (hf == 0) mfma_own<0>(wf, wlds_w, l, ax, aown, acc, t > 0);
    else         mfma_own<1>(wf, wlds_w, l, ax, aown, acc, t > 0);
    if (t > 0) {
      if (hf == 0) mfma_part<0>(wf, wlds_w, l, apart, acc);
      else         mfma_part<1>(wf, wlds_w, l, apart, acc);
    }

    // gates; D layout: col(unit)=l15, row(batch)=4*l4+i
    unsigned short* ho = hbuf + (t & 1) * 4096;
    int ul = 16 * w + l15;
    #pragma unroll
    for (int i = 0; i < 4; ++i) {
      float gg = fast_tanh(acc[0][i]);
      float ii = fast_sigmoid(acc[1][i]);
      float ff = fast_sigmoid(acc[2][i]);
      float oo = fast_sigmoid(acc[3][i]);
      float cc = gg * ii + cst[i] * ff;
      cst[i] = cc;
      float hh = fast_tanh(cc) * oo;
      int r = 4 * l4 + i;
      int gu = hf * 128 + ul;
      ho[r * 256 + (((gu >> 3) ^ r) & 31) * 8 + (gu & 7)] = f2bf(hh);
    }
    __syncthreads();   // B2: h_t complete in LDS

    // publish own half: one plain 8B store per thread (coalesced)
    {
      unsigned long long v = *(const unsigned long long*)(ho + pofs);
      unsigned long long* dst = (unsigned long long*)
          (hxc + (size_t)(((t & 1) * NBG + bgi) * 2 + hf) * 4096);
      dst[(ro * 128 + u0) >> 2] = v;
    }
    __syncthreads();   // B3: all publish stores drained (vmcnt 0 pre-barrier)
    if (tid == 0)
      __hip_atomic_store(myflag, (unsigned)(t + 1), __ATOMIC_RELEASE,
                         __HIP_MEMORY_SCOPE_AGENT);
  }

  // ---- epilogue: half-0 fetches partner h_511, logits + softmax ----
  if (hf == 0) {
    if (w == 0) {
      while (__hip_atomic_load(pflag, __ATOMIC_RELAXED,
                               __HIP_MEMORY_SCOPE_AGENT) < (unsigned)SEQ) {}
      __builtin_amdgcn_fence(__ATOMIC_ACQUIRE, "agent");
      const unsigned short* pp = (const unsigned short*)
          (hxc + (size_t)((1 * NBG + bgi) * 2 + 1) * 4096);
      int er = l >> 2, eu0 = (l & 3) * 32;
      #pragma unroll
      for (int q = 0; q < 4; ++q) {
        u16x8 v = *(const u16x8*)(pp + er * 128 + eu0 + 8 * q);
        int gu = 128 + eu0 + 8 * q;
        *(u16x8*)(hbuf + 4096 + er * 256 + (((gu >> 3) ^ er) & 31) * 8) = v;
      }
    }
    __syncthreads();
    float* lbuf = (float*)(smem + 16384);   // weights LDS dead now
    if (tid < 16 * OD) {
      int eb = tid & 15, ej = tid >> 4;
      float s = bpp[ej];
      for (int k = 0; k < HD; ++k)
        s += bf2f(hbuf[4096 + eb * 256 + (((k >> 3) ^ eb) & 31) * 8 + (k & 7)]) *
             Wph[k * OD + ej];
      lbuf[eb * OD + ej] = s;
    }
    __syncthreads();
    if (tid < 16) {
      float m = -1e30f;
      #pragma unroll
      for (int j = 0; j < OD; ++j) m = fmaxf(m, lbuf[tid * OD + j]);
      float e[OD], sum = 0.f;
      #pragma unroll
      for (int j = 0; j < OD; ++j) { e[j] = __expf(lbuf[tid * OD + j] - m); sum += e[j]; }
      float inv = 1.f / sum;
      #pragma unroll
      for (int j = 0; j < OD; ++j) out[(b0 + tid) * OD + j] = e[j] * inv;
    }
  }
}

extern "C" void kernel_launch(void* const* d_in, const int* in_sizes, int n_in,
                              void* d_out, int out_size, void* d_ws, size_t ws_size,
                              hipStream_t stream) {
  const float* X   = (const float*)d_in[0];
  const float* Wgx = (const float*)d_in[1];
  const float* Wgh = (const float*)d_in[2];
  const float* bg  = (const float*)d_in[3];
  const float* Wix = (const float*)d_in[4];
  const float* Wih = (const float*)d_in[5];
  const float* bi  = (const float*)d_in[6];
  const float* Wfx = (const float*)d_in[7];
  const float* Wfh = (const float*)d_in[8];
  const float* bf  = (const float*)d_in[9];
  const float* Wox = (const float*)d_in[10];
  const float* Woh = (const float*)d_in[11];
  const float* bo  = (const float*)d_in[12];
  const float* Wph = (const float*)d_in[13];
  const float* bp  = (const float*)d_in[14];

  unsigned short* Wpk   = (unsigned short*)d_ws;                     // 576 KB
  unsigned int*   flags = (unsigned int*)((char*)d_ws + FLAGS_OFF);  // 4 KB used
  void*           hx    = (char*)d_ws + HX_OFF;                      // 256 KB

  hipMemsetAsync((char*)d_ws + FLAGS_OFF, 0, 32 * 32 * 4, stream);
  (void)hipFuncSetAttribute((const void*)lstm_rec,
                            hipFuncAttributeMaxDynamicSharedMemorySize,
                            SMEM_BYTES);

  pack_w<<<dim3(72), dim3(512), 0, stream>>>(Wgx, Wgh, Wix, Wih, Wfx, Wfh,
                                             Wox, Woh, Wpk);
  lstm_rec<<<dim3(32), dim3(512), SMEM_BYTES, stream>>>(
      X, Wpk, bg, bi, bf, bo, Wph, bp, flags, hx, (float*)d_out);
}